// Round 7
// baseline (399.185 us; speedup 1.0000x reference)
//
#include <hip/hip_runtime.h>
#include <stdint.h>

// ---------------------------------------------------------------------------
// SingleHeadedAttention (Mega-style, laplacian attn fn, causal, T5 rel bias)
// B=4, S=2048, DIM=1024, DQK=128, DV=1024.  fp32 in/out, bf16 MFMA internals.
// R15: sim+out merged into ONE launch (k_simout) with device-scope
//   producer/consumer flags: removes the sim->out kernel drain and overlaps
//   out blocks with sim's tail. 1568 blocks x 256thr: blocks r<132 (per XCD
//   residue) run TWO sim 64x64 tiles each (2 waves/tile, DEPTH4 full-unroll);
//   rest run R14's LDS-staged out body after acquire-spinning on
//   flags[bt][it] == 4*it+3. Bands it in {c,15-c} pinned per XCD residue c
//   (constant work/XCD); release = per-thread __threadfence + atomicAdd
//   RELEASE; acquire = __hip_atomic_load ACQUIRE (agent scope) -> correct
//   under any blockIdx->XCD mapping. flags zeroed by k_prep each launch.
//   Budget note: harness fill (~42us, 268MB) is inside the timed window.
// R14: qkv+out LDS-staged 128x128 (global_load_lds w=16). R13: XCD-pinned
//   grids, fused prep. R12: out swapped operands. R11: sim TLP fix.
// R10: branchless erf; swapped QK^T.
//   TILED: element (row,k) of [R][K] at
//     ((row>>4)*(K>>5) + (k>>5))*512 + ((k>>3)&3)*128 + (row&15)*8 + (k&7).
// ---------------------------------------------------------------------------

#define B_   4
#define S_   2048
#define DIM_ 1024
#define DQK  128
#define DV   1024
#define NQV  1152

typedef __attribute__((ext_vector_type(8))) short short8;   // 8 bf16
typedef __attribute__((ext_vector_type(4))) float f32x4;    // MFMA C/D

__device__ __forceinline__ uint16_t f32_to_bf16(float f) {
  uint32_t u = __float_as_uint(f);
  u += 0x7FFFu + ((u >> 16) & 1u);          // round-to-nearest-even
  return (uint16_t)(u >> 16);
}

__device__ __forceinline__ uint32_t pack_bf16(float a, float b) {
  return (uint32_t)f32_to_bf16(a) | ((uint32_t)f32_to_bf16(b) << 16);
}

__device__ __forceinline__ float silu_f(float x) {
  return x * __builtin_amdgcn_rcpf(1.0f + __expf(-x));
}

// 0.5*(1+erf((x-mu)/(std*sqrt2))), mu=sqrt(0.5), std=sqrt(pi/4).
// Branchless Abramowitz-Stegun 7.1.26 erf approx, |eps| <= 1.5e-7.
__device__ __forceinline__ float laplacian_attn(float x) {
  float z  = (x - 0.70710678118654752f) * 0.79788456080286536f;
  float az = fabsf(z);
  float t  = __builtin_amdgcn_rcpf(fmaf(0.3275911f, az, 1.0f));
  float w  = fmaf(1.061405429f, t, -1.453152027f);
  w = fmaf(w, t, 1.421413741f);
  w = fmaf(w, t, -0.284496736f);
  w = fmaf(w, t, 0.254829592f);
  float P  = w * t;
  float E  = __expf(-z * z);
  float ea = fmaf(-P, E, 1.0f);            // erf(|z|)
  float er = copysignf(ea, z);
  return fmaf(0.5f, er, 0.5f);
}

// global->LDS DMA, 16B per lane.
__device__ __forceinline__ void gload16(const uint16_t* g, uint16_t* l) {
  __builtin_amdgcn_global_load_lds(
      (const __attribute__((address_space(1))) void*)g,
      (__attribute__((address_space(3))) void*)l, 16, 0, 0);
}

// ---- wave-private MTxNT (16-row units) GEMM on TILED operands -------------
template <int MT, int NT, int DEPTH>
__device__ __forceinline__ void wave_gemm_t(
    const uint16_t* __restrict__ A, int KBa, int rbA,
    const uint16_t* __restrict__ Bt, int KBb, int rbB,
    int nkb, f32x4 acc[MT][NT])
{
  const int lane = threadIdx.x & 63;

  const uint16_t* pa[MT];
  const uint16_t* pb[NT];
  #pragma unroll
  for (int mt = 0; mt < MT; mt++)
    pa[mt] = A + (size_t)(rbA + mt) * KBa * 512 + lane * 8;
  #pragma unroll
  for (int nt = 0; nt < NT; nt++)
    pb[nt] = Bt + (size_t)(rbB + nt) * KBb * 512 + lane * 8;

  #pragma unroll
  for (int mt = 0; mt < MT; mt++)
    #pragma unroll
    for (int nt = 0; nt < NT; nt++) {
      f32x4 z = {0.0f, 0.0f, 0.0f, 0.0f};
      acc[mt][nt] = z;
    }

  short8 fa0[MT], fb0[NT], fa1[MT], fb1[NT];

  auto loads = [&](short8 fa[MT], short8 fb[NT], int kb) {
    #pragma unroll
    for (int mt = 0; mt < MT; mt++)
      fa[mt] = *(const short8*)(pa[mt] + (size_t)kb * 512);
    #pragma unroll
    for (int nt = 0; nt < NT; nt++)
      fb[nt] = *(const short8*)(pb[nt] + (size_t)kb * 512);
  };
  auto mfmas = [&](short8 fa[MT], short8 fb[NT]) {
    #pragma unroll
    for (int mt = 0; mt < MT; mt++)
      #pragma unroll
      for (int nt = 0; nt < NT; nt++)
        acc[mt][nt] = __builtin_amdgcn_mfma_f32_16x16x32_bf16(
            fa[mt], fb[nt], acc[mt][nt], 0, 0, 0);
  };

  if constexpr (DEPTH == 2) {
    loads(fa0, fb0, 0);
    loads(fa1, fb1, 1);
    for (int kb = 2; kb < nkb; kb += 2) {
      mfmas(fa0, fb0);
      loads(fa0, fb0, kb);
      mfmas(fa1, fb1);
      loads(fa1, fb1, kb + 1);
    }
    mfmas(fa0, fb0);
    mfmas(fa1, fb1);
  } else {
    short8 fa2[MT], fb2[NT], fa3[MT], fb3[NT];
    loads(fa0, fb0, 0);
    loads(fa1, fb1, 1);
    loads(fa2, fb2, 2);
    loads(fa3, fb3, 3);
    for (int kb = 4; kb < nkb; kb += 4) {
      mfmas(fa0, fb0);
      loads(fa0, fb0, kb);
      mfmas(fa1, fb1);
      loads(fa1, fb1, kb + 1);
      mfmas(fa2, fb2);
      loads(fa2, fb2, kb + 2);
      mfmas(fa3, fb3);
      loads(fa3, fb3, kb + 3);
    }
    mfmas(fa0, fb0);
    mfmas(fa1, fb1);
    mfmas(fa2, fb2);
    mfmas(fa3, fb3);
  }
}

#define WAVE_PREAMBLE                                  \
  int lane = threadIdx.x & 63;                         \
  int wave = threadIdx.x >> 6;                         \
  int lane16 = lane & 15;                              \
  int quad = lane >> 4;                                \
  int wrow = (wave >> 1) * 64;                         \
  int wcol = (wave & 1) * 64;

// ---- fused prep kernel -----------------------------------------------------
__global__ __launch_bounds__(256) void k_prep(
    const float* __restrict__ x, const float* __restrict__ wqk,
    const float* __restrict__ wv, const float* __restrict__ rel,
    uint16_t* __restrict__ xb, uint16_t* __restrict__ wT,
    float* __restrict__ bias_n, uint32_t* __restrict__ flags)
{
  int blk = blockIdx.x;
  if (blk < 4096) {
    int t = blk * 256 + threadIdx.x;           // 0 .. 8192*128-1
    int i16 = t & 15, oct = (t >> 4) & 3, kb = (t >> 6) & 31, ib = t >> 11;
    const float* src = x + (size_t)(ib * 16 + i16) * DIM_ + kb * 32 + oct * 8;
    float4 a = *(const float4*)src;
    float4 b = *(const float4*)(src + 4);
    short8 o;
    o[0] = f32_to_bf16(a.x); o[1] = f32_to_bf16(a.y);
    o[2] = f32_to_bf16(a.z); o[3] = f32_to_bf16(a.w);
    o[4] = f32_to_bf16(b.x); o[5] = f32_to_bf16(b.y);
    o[6] = f32_to_bf16(b.z); o[7] = f32_to_bf16(b.w);
    *(short8*)(xb + (size_t)t * 8) = o;
  } else if (blk < 4672) {
    int t = (blk - 4096) * 256 + threadIdx.x;  // 0 .. 1152*128-1
    int n16 = t & 15, oct = (t >> 4) & 3, kb = (t >> 6) & 31, nb = t >> 11;
    int n = nb * 16 + n16;
    int k0 = kb * 32 + oct * 8;
    short8 o;
    if (n < DQK) {
      #pragma unroll
      for (int j = 0; j < 8; j++)
        o[j] = f32_to_bf16(wqk[(size_t)(k0 + j) * DQK + n]);
    } else {
      int nn = n - DQK;
      #pragma unroll
      for (int j = 0; j < 8; j++)
        o[j] = f32_to_bf16(wv[(size_t)(k0 + j) * DV + nn]);
    }
    *(short8*)(wT + (size_t)t * 8) = o;
  } else {
    for (int n = threadIdx.x; n < S_; n += 256) {
      int bucket;
      if (n < 16) {
        bucket = n;
      } else {
        float tt = logf((float)n * 0.0625f) / 2.0794415416798357f * 16.0f;
        int vl = 16 + (int)tt;
        bucket = vl < 31 ? vl : 31;
      }
      bias_n[n] = rel[bucket] * 11.313708498984761f;
    }
    if (threadIdx.x < 64) flags[threadIdx.x] = 0u;   // [bt][it] counters
  }
}

// ---- fused projections (unchanged from R14) --------------------------------
__global__ __launch_bounds__(256, 3) void k_gemm_qkv(
    const uint16_t* __restrict__ xb, const uint16_t* __restrict__ wT,
    const float* __restrict__ bqk, const float* __restrict__ gamma,
    const float* __restrict__ beta, const float* __restrict__ bv,
    uint16_t* __restrict__ qb, uint16_t* __restrict__ kb,
    uint16_t* __restrict__ vT)
{
  int L = blockIdx.x;                    // 0..575
  int c = L & 7;
  int idx = L >> 3;                      // 0..71
  int by = c + 8 * (idx / 9);
  int bx = idx % 9;
  WAVE_PREAMBLE

  __shared__ uint16_t sA[8 * 2 * 512];   // [rbu][kk][512]
  __shared__ uint16_t sB[8 * 2 * 512];

  const uint16_t *Ab, *Bb;
  if (bx == 0) { Ab = wT;                              Bb = xb + (size_t)by * 8 * 32 * 512; }
  else         { Ab = xb + (size_t)by * 8 * 32 * 512;  Bb = wT + (size_t)bx * 8 * 32 * 512; }

  const uint16_t* gp = (wave >> 1) ? Bb : Ab;
  uint16_t*       sp = (wave >> 1) ? sB : sA;
  int rb0 = (wave & 1) * 4;

  f32x4 acc[4][4];
  #pragma unroll
  for (int mt = 0; mt < 4; mt++)
    #pragma unroll
    for (int nt = 0; nt < 4; nt++) {
      f32x4 z = {0.0f, 0.0f, 0.0f, 0.0f};
      acc[mt][nt] = z;
    }

  for (int kbi = 0; kbi < 32; kbi += 2) {
    #pragma unroll
    for (int uu = 0; uu < 8; uu++) {
      int rbu = rb0 + (uu >> 1), kk = uu & 1;
      gload16(gp + ((size_t)rbu * 32 + kbi + kk) * 512 + lane * 8,
              sp + (rbu * 2 + kk) * 512);
    }
    __syncthreads();
    #pragma unroll
    for (int kk = 0; kk < 2; kk++) {
      short8 fa[4], fb[4];
      #pragma unroll
      for (int mt = 0; mt < 4; mt++)
        fa[mt] = *(const short8*)(sA + (((wave >> 1) * 4 + mt) * 2 + kk) * 512 + lane * 8);
      #pragma unroll
      for (int nt = 0; nt < 4; nt++)
        fb[nt] = *(const short8*)(sB + (((wave & 1) * 4 + nt) * 2 + kk) * 512 + lane * 8);
      #pragma unroll
      for (int mt = 0; mt < 4; mt++)
        #pragma unroll
        for (int nt = 0; nt < 4; nt++)
          acc[mt][nt] = __builtin_amdgcn_mfma_f32_16x16x32_bf16(
              fa[mt], fb[nt], acc[mt][nt], 0, 0, 0);
    }
    __syncthreads();
  }

  if (bx == 0) {
    int ibase = by * 128 + (wave & 1) * 64;
    int cbase = (wave >> 1) * 64;
    #pragma unroll
    for (int mt = 0; mt < 4; mt++) {
      int c0 = cbase + mt * 16 + quad * 4;
      float4 bb = *(const float4*)(bqk + c0);
      float4 g0 = *(const float4*)(gamma + c0);
      float4 g1 = *(const float4*)(gamma + DQK + c0);
      float4 e0 = *(const float4*)(beta + c0);
      float4 e1 = *(const float4*)(beta + DQK + c0);
      size_t coff = (size_t)(c0 >> 5) * 512 + ((c0 >> 3) & 3) * 128 + (c0 & 7);
      #pragma unroll
      for (int nt = 0; nt < 4; nt++) {
        int i = ibase + nt * 16 + lane16;
        float s0 = silu_f(acc[mt][nt][0] + bb.x);
        float s1 = silu_f(acc[mt][nt][1] + bb.y);
        float s2 = silu_f(acc[mt][nt][2] + bb.z);
        float s3 = silu_f(acc[mt][nt][3] + bb.w);
        uint2 pq, pk;
        pq.x = pack_bf16(fmaf(s0, g0.x, e0.x), fmaf(s1, g0.y, e0.y));
        pq.y = pack_bf16(fmaf(s2, g0.z, e0.z), fmaf(s3, g0.w, e0.w));
        pk.x = pack_bf16(fmaf(s0, g1.x, e1.x), fmaf(s1, g1.y, e1.y));
        pk.y = pack_bf16(fmaf(s2, g1.z, e1.z), fmaf(s3, g1.w, e1.w));
        size_t off = (size_t)(i >> 4) * 4 * 512 + (size_t)(i & 15) * 8 + coff;
        *(uint2*)(qb + off) = pq;
        *(uint2*)(kb + off) = pk;
      }
    }
  } else {
    int b = by >> 4;                               // batch (by*128 / 2048)
    uint16_t* vt = vT + (size_t)b * DV * S_;
    #pragma unroll
    for (int nt = 0; nt < 4; nt++) {
      int n = (bx - 1) * 128 + wcol + nt * 16 + lane16;   // 0..1023
      float bb = bv[n];
      #pragma unroll
      for (int mt = 0; mt < 4; mt++) {
        int j0l = (by & 15) * 128 + wrow + mt * 16 + quad * 4; // local seq
        uint16_t v0 = f32_to_bf16(silu_f(acc[mt][nt][0] + bb));
        uint16_t v1 = f32_to_bf16(silu_f(acc[mt][nt][1] + bb));
        uint16_t v2 = f32_to_bf16(silu_f(acc[mt][nt][2] + bb));
        uint16_t v3 = f32_to_bf16(silu_f(acc[mt][nt][3] + bb));
        size_t off = (size_t)((n >> 4) * 64 + (j0l >> 5)) * 512 +
                     ((j0l >> 3) & 3) * 128 + (n & 15) * 8 + (j0l & 7);
        uint2 pk;
        pk.x = (uint32_t)v0 | ((uint32_t)v1 << 16);
        pk.y = (uint32_t)v2 | ((uint32_t)v3 << 16);
        *(uint2*)(vt + off) = pk;
      }
    }
  }
}

// ---- merged sim + out ------------------------------------------------------
// Grid 1568 x 256thr. c = L&7 (XCD residue), r = L>>3 (0..195).
//   r < 132 : sim pair-block. Per XCD: 264 tiles = all causal 64x64 tiles of
//             bands it in {15-c (H), c (Lo)} x 4 batches; tiles 2r, 2r+1 run
//             on waves {0,1} / {2,3}. After stores: threadfence + syncthreads
//             + release-add flags[bt*16 + it64>>1].
//   r >= 132: out block o = r-132: it = o<32 ? H : Lo; bt=(o>>3)&3; nx=o&7.
//             Acquire-spin until flags[bt*16+it] == 4*it+3, then R14 body.
__global__ __launch_bounds__(256, 3) void k_simout(
    const uint16_t* __restrict__ qb, const uint16_t* __restrict__ kb,
    const float* __restrict__ bias_n, uint16_t* attn,
    const uint16_t* __restrict__ vT, float* __restrict__ out,
    uint32_t* flags)
{
  int Lb = blockIdx.x;
  int c = Lb & 7, r = Lb >> 3;
  int H = 15 - c;

  __shared__ uint16_t sA[8 * 2 * 512];
  __shared__ uint16_t sB[8 * 2 * 512];

  int lane = threadIdx.x & 63;
  int wave = threadIdx.x >> 6;
  int lane16 = lane & 15;
  int quad = lane >> 4;

  if (r < 132) {
    // ---- sim pair ----
    int t = 2 * r + (wave >> 1);         // tile index in this XCD's list
    int bt, it64, jt;
    {
      int nHt = 4 * H + 3, baseH = 4 * nHt;
      if (t < baseH) {
        bt = t / nHt;
        int u = t - bt * nHt;
        if (u <= 2 * H) { it64 = 2 * H; jt = u; }
        else            { it64 = 2 * H + 1; jt = u - (2 * H + 1); }
      } else {
        int nLt = 4 * c + 3;
        int t2 = t - baseH;
        bt = t2 / nLt;
        int u = t2 - bt * nLt;
        if (u <= 2 * c) { it64 = 2 * c; jt = u; }
        else            { it64 = 2 * c + 1; jt = u - (2 * c + 1); }
      }
    }
    int wv = wave & 1;                   // i-half of the 64-row tile

    f32x4 acc[4][2];
    wave_gemm_t<4,2,4>(kb, 4, bt * 128 + jt * 4,
                       qb, 4, bt * 128 + it64 * 4 + wv * 2,
                       4, acc);

    uint16_t* ab = attn + (size_t)bt * S_ * S_;
    int ibase = it64 * 64 + wv * 32;
    int jbase = jt * 64;
    #pragma unroll
    for (int nt = 0; nt < 2; nt++) {
      int i = ibase + nt * 16 + lane16;
      size_t irow = (size_t)(i >> 4) * 64 * 512 + (size_t)(i & 15) * 8;
      #pragma unroll
      for (int mt = 0; mt < 4; mt++) {
        int j0 = jbase + mt * 16 + quad * 4;
        float v[4];
        #pragma unroll
        for (int rr = 0; rr < 4; rr++) {
          int j = j0 + rr;
          float aval = 0.0f;
          if (j <= i) {
            float sim = acc[mt][nt][rr] * (1.0f / 2048.0f) + bias_n[i - j];
            aval = laplacian_attn(sim);
          }
          v[rr] = aval;
        }
        uint2 pk;
        pk.x = pack_bf16(v[0], v[1]);
        pk.y = pack_bf16(v[2], v[3]);
        size_t off = irow + (size_t)(j0 >> 5) * 512 + ((j0 >> 3) & 3) * 128 +
                     (j0 & 7);
        *(uint2*)(ab + off) = pk;
      }
    }

    __threadfence();
    __syncthreads();
    if ((threadIdx.x & 127) == 0)
      __hip_atomic_fetch_add(&flags[bt * 16 + (it64 >> 1)], 1u,
                             __ATOMIC_RELEASE, __HIP_MEMORY_SCOPE_AGENT);
  } else {
    // ---- out block ----
    int o = r - 132;
    int it = (o < 32) ? H : c;
    int bt = (o >> 3) & 3, nx = o & 7;
    int nkb = 4 * it + 4;                // causal K bound (k-blocks, even)

    if (threadIdx.x == 0) {
      while (__hip_atomic_load(&flags[bt * 16 + it], __ATOMIC_ACQUIRE,
                               __HIP_MEMORY_SCOPE_AGENT) < (uint32_t)(4 * it + 3))
        __builtin_amdgcn_s_sleep(2);
    }
    __syncthreads();

    int wrow = (wave >> 1) * 64;
    int wcol = (wave & 1) * 64;

    const uint16_t* Ab = vT + (size_t)bt * DV * S_ + (size_t)nx * 8 * 64 * 512;
    const uint16_t* Bb = attn + (size_t)bt * S_ * S_ + (size_t)it * 8 * 64 * 512;

    const uint16_t* gp = (wave >> 1) ? Bb : Ab;
    uint16_t*       sp = (wave >> 1) ? sB : sA;
    int rb0 = (wave & 1) * 4;

    f32x4 acc[4][4];
    #pragma unroll
    for (int mt = 0; mt < 4; mt++)
      #pragma unroll
      for (int nt = 0; nt < 4; nt++) {
        f32x4 z = {0.0f, 0.0f, 0.0f, 0.0f};
        acc[mt][nt] = z;
      }

    for (int kbi = 0; kbi < nkb; kbi += 2) {
      #pragma unroll
      for (int uu = 0; uu < 8; uu++) {
        int rbu = rb0 + (uu >> 1), kk = uu & 1;
        gload16(gp + ((size_t)rbu * 64 + kbi + kk) * 512 + lane * 8,
                sp + (rbu * 2 + kk) * 512);
      }
      __syncthreads();
      #pragma unroll
      for (int kk = 0; kk < 2; kk++) {
        short8 fa[4], fb[4];
        #pragma unroll
        for (int mt = 0; mt < 4; mt++)
          fa[mt] = *(const short8*)(sA + (((wave & 1) * 4 + mt) * 2 + kk) * 512 + lane * 8);
        #pragma unroll
        for (int nt = 0; nt < 4; nt++)
          fb[nt] = *(const short8*)(sB + (((wave >> 1) * 4 + nt) * 2 + kk) * 512 + lane * 8);
        #pragma unroll
        for (int mt = 0; mt < 4; mt++)
          #pragma unroll
          for (int nt = 0; nt < 4; nt++)
            acc[mt][nt] = __builtin_amdgcn_mfma_f32_16x16x32_bf16(
                fa[mt], fb[nt], acc[mt][nt], 0, 0, 0);
      }
      __syncthreads();
    }

    float* ob = out + ((size_t)bt * S_ + it * 128 + wrow) * DV + nx * 128 + wcol;
    #pragma unroll
    for (int nt = 0; nt < 4; nt++) {
      int i = nt * 16 + lane16;
      #pragma unroll
      for (int mt = 0; mt < 4; mt++) {
        int n = mt * 16 + quad * 4;
        *(float4*)(ob + (size_t)i * DV + n) = *(float4*)&acc[mt][nt];
      }
    }
  }
}

// ---------------------------------------------------------------------------

extern "C" void kernel_launch(void* const* d_in, const int* in_sizes, int n_in,
                              void* d_out, int out_size, void* d_ws, size_t ws_size,
                              hipStream_t stream)
{
  const float* x     = (const float*)d_in[0];
  const float* wqk   = (const float*)d_in[1];
  const float* bqk   = (const float*)d_in[2];
  const float* gamma = (const float*)d_in[3];
  const float* beta  = (const float*)d_in[4];
  const float* wv    = (const float*)d_in[5];
  const float* bv    = (const float*)d_in[6];
  const float* rel   = (const float*)d_in[7];
  float* out = (float*)d_out;

  char* ws = (char*)d_ws;
  size_t off = 0;
  uint16_t* xb     = (uint16_t*)(ws + off); off += (size_t)B_ * S_ * DIM_ * 2;  // 16 MB
  uint16_t* wT     = (uint16_t*)(ws + off); off += (size_t)NQV * DIM_ * 2;      // 2.25 MB
  uint16_t* qb     = (uint16_t*)(ws + off); off += (size_t)B_ * S_ * DQK * 2;   // 2 MB
  uint16_t* kb     = (uint16_t*)(ws + off); off += (size_t)B_ * S_ * DQK * 2;   // 2 MB
  uint16_t* vT     = (uint16_t*)(ws + off); off += (size_t)B_ * DV * S_ * 2;    // 16 MB
  uint16_t* attn   = (uint16_t*)(ws + off); off += (size_t)B_ * S_ * S_ * 2;    // 32 MB
  float*    bias_n = (float*)(ws + off);    off += (size_t)S_ * 4;              // 8 KB
  uint32_t* flags  = (uint32_t*)(ws + off); off += 64 * 4;                      // 256 B

  k_prep<<<dim3(4673), dim3(256), 0, stream>>>(x, wqk, wv, rel, xb, wT,
                                               bias_n, flags);
  k_gemm_qkv<<<dim3(576), dim3(256), 0, stream>>>(
      xb, wT, bqk, gamma, beta, bv, qb, kb, vT);
  k_simout<<<dim3(1568), dim3(256), 0, stream>>>(
      qb, kb, bias_n, attn, vT, out, flags);
}

// Round 8
// 183.519 us; speedup vs baseline: 2.1752x; 2.1752x over previous
//
#include <hip/hip_runtime.h>
#include <stdint.h>

// ---------------------------------------------------------------------------
// SingleHeadedAttention (Mega-style, laplacian attn fn, causal, T5 rel bias)
// B=4, S=2048, DIM=1024, DQK=128, DV=1024.  fp32 in/out, bf16 MFMA internals.
// R16: R15's flag-sync merge REVERTED (agent-scope fences + spin = 399us).
//   Safe-fusion instead: sim and v-projection are mutually independent ->
//   one launch, disjoint block ranges, NO cross-block communication:
//     k_prep -> k_gemm_qk (64 blocks, q/k only) -> k_simv (1056 sim-pair
//     blocks + 512 v blocks) -> k_gemm_out.
//   Serial chain qkv->sim becomes qk->max(sim,v). k_simv at (256,4) keeps
//   sim's TLP (~16 waves/CU); sim pairs DEPTH4 (single latency exposure,
//   VGPR fits: R15 measured 60 VGPR for a superset kernel).
// R14: LDS-staged 128x128 GEMM bodies (global_load_lds w=16, BK=64,
//   2-barrier loop). R13: XCD-pinned grids, fused prep. R12: out swapped
//   operands (float4 stores), LPT. R11: sim 32x64 wave tiles, triangle grid.
// R10: branchless erf; swapped QK^T.
//   TILED: element (row,k) of [R][K] at
//     ((row>>4)*(K>>5) + (k>>5))*512 + ((k>>3)&3)*128 + (row&15)*8 + (k&7).
// ---------------------------------------------------------------------------

#define B_   4
#define S_   2048
#define DIM_ 1024
#define DQK  128
#define DV   1024
#define NQV  1152

typedef __attribute__((ext_vector_type(8))) short short8;   // 8 bf16
typedef __attribute__((ext_vector_type(4))) float f32x4;    // MFMA C/D

__device__ __forceinline__ uint16_t f32_to_bf16(float f) {
  uint32_t u = __float_as_uint(f);
  u += 0x7FFFu + ((u >> 16) & 1u);          // round-to-nearest-even
  return (uint16_t)(u >> 16);
}

__device__ __forceinline__ uint32_t pack_bf16(float a, float b) {
  return (uint32_t)f32_to_bf16(a) | ((uint32_t)f32_to_bf16(b) << 16);
}

__device__ __forceinline__ float silu_f(float x) {
  return x * __builtin_amdgcn_rcpf(1.0f + __expf(-x));
}

// 0.5*(1+erf((x-mu)/(std*sqrt2))), mu=sqrt(0.5), std=sqrt(pi/4).
// Branchless Abramowitz-Stegun 7.1.26 erf approx, |eps| <= 1.5e-7.
__device__ __forceinline__ float laplacian_attn(float x) {
  float z  = (x - 0.70710678118654752f) * 0.79788456080286536f;
  float az = fabsf(z);
  float t  = __builtin_amdgcn_rcpf(fmaf(0.3275911f, az, 1.0f));
  float w  = fmaf(1.061405429f, t, -1.453152027f);
  w = fmaf(w, t, 1.421413741f);
  w = fmaf(w, t, -0.284496736f);
  w = fmaf(w, t, 0.254829592f);
  float P  = w * t;
  float E  = __expf(-z * z);
  float ea = fmaf(-P, E, 1.0f);            // erf(|z|)
  float er = copysignf(ea, z);
  return fmaf(0.5f, er, 0.5f);
}

// global->LDS DMA, 16B per lane.
__device__ __forceinline__ void gload16(const uint16_t* g, uint16_t* l) {
  __builtin_amdgcn_global_load_lds(
      (const __attribute__((address_space(1))) void*)g,
      (__attribute__((address_space(3))) void*)l, 16, 0, 0);
}

// ---- wave-private MTxNT (16-row units) GEMM on TILED operands -------------
template <int MT, int NT, int DEPTH>
__device__ __forceinline__ void wave_gemm_t(
    const uint16_t* __restrict__ A, int KBa, int rbA,
    const uint16_t* __restrict__ Bt, int KBb, int rbB,
    int nkb, f32x4 acc[MT][NT])
{
  const int lane = threadIdx.x & 63;

  const uint16_t* pa[MT];
  const uint16_t* pb[NT];
  #pragma unroll
  for (int mt = 0; mt < MT; mt++)
    pa[mt] = A + (size_t)(rbA + mt) * KBa * 512 + lane * 8;
  #pragma unroll
  for (int nt = 0; nt < NT; nt++)
    pb[nt] = Bt + (size_t)(rbB + nt) * KBb * 512 + lane * 8;

  #pragma unroll
  for (int mt = 0; mt < MT; mt++)
    #pragma unroll
    for (int nt = 0; nt < NT; nt++) {
      f32x4 z = {0.0f, 0.0f, 0.0f, 0.0f};
      acc[mt][nt] = z;
    }

  short8 fa0[MT], fb0[NT], fa1[MT], fb1[NT];

  auto loads = [&](short8 fa[MT], short8 fb[NT], int kb) {
    #pragma unroll
    for (int mt = 0; mt < MT; mt++)
      fa[mt] = *(const short8*)(pa[mt] + (size_t)kb * 512);
    #pragma unroll
    for (int nt = 0; nt < NT; nt++)
      fb[nt] = *(const short8*)(pb[nt] + (size_t)kb * 512);
  };
  auto mfmas = [&](short8 fa[MT], short8 fb[NT]) {
    #pragma unroll
    for (int mt = 0; mt < MT; mt++)
      #pragma unroll
      for (int nt = 0; nt < NT; nt++)
        acc[mt][nt] = __builtin_amdgcn_mfma_f32_16x16x32_bf16(
            fa[mt], fb[nt], acc[mt][nt], 0, 0, 0);
  };

  if constexpr (DEPTH == 2) {
    loads(fa0, fb0, 0);
    loads(fa1, fb1, 1);
    for (int kb = 2; kb < nkb; kb += 2) {
      mfmas(fa0, fb0);
      loads(fa0, fb0, kb);
      mfmas(fa1, fb1);
      loads(fa1, fb1, kb + 1);
    }
    mfmas(fa0, fb0);
    mfmas(fa1, fb1);
  } else {
    short8 fa2[MT], fb2[NT], fa3[MT], fb3[NT];
    loads(fa0, fb0, 0);
    loads(fa1, fb1, 1);
    loads(fa2, fb2, 2);
    loads(fa3, fb3, 3);
    for (int kb = 4; kb < nkb; kb += 4) {
      mfmas(fa0, fb0);
      loads(fa0, fb0, kb);
      mfmas(fa1, fb1);
      loads(fa1, fb1, kb + 1);
      mfmas(fa2, fb2);
      loads(fa2, fb2, kb + 2);
      mfmas(fa3, fb3);
      loads(fa3, fb3, kb + 3);
    }
    mfmas(fa0, fb0);
    mfmas(fa1, fb1);
    mfmas(fa2, fb2);
    mfmas(fa3, fb3);
  }
}

// ---- fused prep kernel -----------------------------------------------------
__global__ __launch_bounds__(256) void k_prep(
    const float* __restrict__ x, const float* __restrict__ wqk,
    const float* __restrict__ wv, const float* __restrict__ rel,
    uint16_t* __restrict__ xb, uint16_t* __restrict__ wT,
    float* __restrict__ bias_n)
{
  int blk = blockIdx.x;
  if (blk < 4096) {
    int t = blk * 256 + threadIdx.x;           // 0 .. 8192*128-1
    int i16 = t & 15, oct = (t >> 4) & 3, kb = (t >> 6) & 31, ib = t >> 11;
    const float* src = x + (size_t)(ib * 16 + i16) * DIM_ + kb * 32 + oct * 8;
    float4 a = *(const float4*)src;
    float4 b = *(const float4*)(src + 4);
    short8 o;
    o[0] = f32_to_bf16(a.x); o[1] = f32_to_bf16(a.y);
    o[2] = f32_to_bf16(a.z); o[3] = f32_to_bf16(a.w);
    o[4] = f32_to_bf16(b.x); o[5] = f32_to_bf16(b.y);
    o[6] = f32_to_bf16(b.z); o[7] = f32_to_bf16(b.w);
    *(short8*)(xb + (size_t)t * 8) = o;
  } else if (blk < 4672) {
    int t = (blk - 4096) * 256 + threadIdx.x;  // 0 .. 1152*128-1
    int n16 = t & 15, oct = (t >> 4) & 3, kb = (t >> 6) & 31, nb = t >> 11;
    int n = nb * 16 + n16;
    int k0 = kb * 32 + oct * 8;
    short8 o;
    if (n < DQK) {
      #pragma unroll
      for (int j = 0; j < 8; j++)
        o[j] = f32_to_bf16(wqk[(size_t)(k0 + j) * DQK + n]);
    } else {
      int nn = n - DQK;
      #pragma unroll
      for (int j = 0; j < 8; j++)
        o[j] = f32_to_bf16(wv[(size_t)(k0 + j) * DV + nn]);
    }
    *(short8*)(wT + (size_t)t * 8) = o;
  } else {
    for (int n = threadIdx.x; n < S_; n += 256) {
      int bucket;
      if (n < 16) {
        bucket = n;
      } else {
        float tt = logf((float)n * 0.0625f) / 2.0794415416798357f * 16.0f;
        int vl = 16 + (int)tt;
        bucket = vl < 31 ? vl : 31;
      }
      bias_n[n] = rel[bucket] * 11.313708498984761f;
    }
  }
}

// ---- q/k projection only (was qkv bx==0), grid 64 --------------------------
// SWAPPED operands (A=wT dqk cols, B=xb rows) -> packed 8B q/k stores.
__global__ __launch_bounds__(256, 3) void k_gemm_qk(
    const uint16_t* __restrict__ xb, const uint16_t* __restrict__ wT,
    const float* __restrict__ bqk, const float* __restrict__ gamma,
    const float* __restrict__ beta,
    uint16_t* __restrict__ qb, uint16_t* __restrict__ kb)
{
  int L = blockIdx.x;                    // 0..63
  int by = (L & 7) + 8 * (L >> 3);
  int lane = threadIdx.x & 63;
  int wave = threadIdx.x >> 6;
  int lane16 = lane & 15;
  int quad = lane >> 4;

  __shared__ uint16_t sA[8 * 2 * 512];   // [rbu][kk][512]
  __shared__ uint16_t sB[8 * 2 * 512];

  const uint16_t* Ab = wT;
  const uint16_t* Bb = xb + (size_t)by * 8 * 32 * 512;

  const uint16_t* gp = (wave >> 1) ? Bb : Ab;
  uint16_t*       sp = (wave >> 1) ? sB : sA;
  int rb0 = (wave & 1) * 4;

  f32x4 acc[4][4];
  #pragma unroll
  for (int mt = 0; mt < 4; mt++)
    #pragma unroll
    for (int nt = 0; nt < 4; nt++) {
      f32x4 z = {0.0f, 0.0f, 0.0f, 0.0f};
      acc[mt][nt] = z;
    }

  for (int kbi = 0; kbi < 32; kbi += 2) {
    #pragma unroll
    for (int uu = 0; uu < 8; uu++) {
      int rbu = rb0 + (uu >> 1), kk = uu & 1;
      gload16(gp + ((size_t)rbu * 32 + kbi + kk) * 512 + lane * 8,
              sp + (rbu * 2 + kk) * 512);
    }
    __syncthreads();
    #pragma unroll
    for (int kk = 0; kk < 2; kk++) {
      short8 fa[4], fb[4];
      #pragma unroll
      for (int mt = 0; mt < 4; mt++)
        fa[mt] = *(const short8*)(sA + (((wave >> 1) * 4 + mt) * 2 + kk) * 512 + lane * 8);
      #pragma unroll
      for (int nt = 0; nt < 4; nt++)
        fb[nt] = *(const short8*)(sB + (((wave & 1) * 4 + nt) * 2 + kk) * 512 + lane * 8);
      #pragma unroll
      for (int mt = 0; mt < 4; mt++)
        #pragma unroll
        for (int nt = 0; nt < 4; nt++)
          acc[mt][nt] = __builtin_amdgcn_mfma_f32_16x16x32_bf16(
              fa[mt], fb[nt], acc[mt][nt], 0, 0, 0);
    }
    __syncthreads();
  }

  int ibase = by * 128 + (wave & 1) * 64;
  int cbase = (wave >> 1) * 64;
  #pragma unroll
  for (int mt = 0; mt < 4; mt++) {
    int c0 = cbase + mt * 16 + quad * 4;
    float4 bb = *(const float4*)(bqk + c0);
    float4 g0 = *(const float4*)(gamma + c0);
    float4 g1 = *(const float4*)(gamma + DQK + c0);
    float4 e0 = *(const float4*)(beta + c0);
    float4 e1 = *(const float4*)(beta + DQK + c0);
    size_t coff = (size_t)(c0 >> 5) * 512 + ((c0 >> 3) & 3) * 128 + (c0 & 7);
    #pragma unroll
    for (int nt = 0; nt < 4; nt++) {
      int i = ibase + nt * 16 + lane16;
      float s0 = silu_f(acc[mt][nt][0] + bb.x);
      float s1 = silu_f(acc[mt][nt][1] + bb.y);
      float s2 = silu_f(acc[mt][nt][2] + bb.z);
      float s3 = silu_f(acc[mt][nt][3] + bb.w);
      uint2 pq, pk;
      pq.x = pack_bf16(fmaf(s0, g0.x, e0.x), fmaf(s1, g0.y, e0.y));
      pq.y = pack_bf16(fmaf(s2, g0.z, e0.z), fmaf(s3, g0.w, e0.w));
      pk.x = pack_bf16(fmaf(s0, g1.x, e1.x), fmaf(s1, g1.y, e1.y));
      pk.y = pack_bf16(fmaf(s2, g1.z, e1.z), fmaf(s3, g1.w, e1.w));
      size_t off = (size_t)(i >> 4) * 4 * 512 + (size_t)(i & 15) * 8 + coff;
      *(uint2*)(qb + off) = pq;
      *(uint2*)(kb + off) = pk;
    }
  }
}

// ---- sim + v-projection in ONE launch (independent block ranges) -----------
// Lb < 1056: sim pair — two 64x64 causal tiles (waves {0,1}, {2,3}); flat
//   t = 2*Lb + (wave>>1) over 2112 tiles; bt = t/528; triangle decode on rem.
//   SWAPPED QK^T (A=kb j-rows, B=qb i-rows); DEPTH4 (nkb=4, single exposure).
// Lb >= 1056: v block o = Lb-1056: XCD c=o&7 owns by in {c, c+8, ..}:
//   by = c + 8*((o>>3)&7), bx = 1 + (o>>6). R14 LDS-staged body -> vT TILED.
// No cross-block deps anywhere: sim reads qb/kb/bias, v reads xb/wT.
__global__ __launch_bounds__(256, 4) void k_simv(
    const uint16_t* __restrict__ qb, const uint16_t* __restrict__ kb,
    const float* __restrict__ bias_n, uint16_t* __restrict__ attn,
    const uint16_t* __restrict__ xb, const uint16_t* __restrict__ wT,
    const float* __restrict__ bv, uint16_t* __restrict__ vT)
{
  int Lb = blockIdx.x;
  int lane = threadIdx.x & 63;
  int wave = threadIdx.x >> 6;
  int lane16 = lane & 15;
  int quad = lane >> 4;

  __shared__ uint16_t sA[8 * 2 * 512];
  __shared__ uint16_t sB[8 * 2 * 512];

  if (Lb < 1056) {
    // ---- sim pair ----
    int t = 2 * Lb + (wave >> 1);        // 0..2111
    int bt = t / 528;
    int u = t - bt * 528;                // 0..527
    int it = (int)((sqrtf(8.0f * (float)u + 1.0f) - 1.0f) * 0.5f);
    while ((it + 1) * (it + 2) / 2 <= u) ++it;
    while (it * (it + 1) / 2 > u) --it;
    int jt = u - it * (it + 1) / 2;      // 0..it  (64-row bands, it 0..31)
    int wv = wave & 1;

    f32x4 acc[4][2];
    wave_gemm_t<4,2,4>(kb, 4, bt * 128 + jt * 4,
                       qb, 4, bt * 128 + it * 4 + wv * 2,
                       4, acc);

    uint16_t* ab = attn + (size_t)bt * S_ * S_;
    int ibase = it * 64 + wv * 32;
    int jbase = jt * 64;
    #pragma unroll
    for (int nt = 0; nt < 2; nt++) {
      int i = ibase + nt * 16 + lane16;
      size_t irow = (size_t)(i >> 4) * 64 * 512 + (size_t)(i & 15) * 8;
      #pragma unroll
      for (int mt = 0; mt < 4; mt++) {
        int j0 = jbase + mt * 16 + quad * 4;
        float v[4];
        #pragma unroll
        for (int rr = 0; rr < 4; rr++) {
          int j = j0 + rr;
          float aval = 0.0f;
          if (j <= i) {
            float sim = acc[mt][nt][rr] * (1.0f / 2048.0f) + bias_n[i - j];
            aval = laplacian_attn(sim);
          }
          v[rr] = aval;
        }
        uint2 pk;
        pk.x = pack_bf16(v[0], v[1]);
        pk.y = pack_bf16(v[2], v[3]);
        size_t off = irow + (size_t)(j0 >> 5) * 512 + ((j0 >> 3) & 3) * 128 +
                     (j0 & 7);
        *(uint2*)(ab + off) = pk;
      }
    }
  } else {
    // ---- v-projection block (R14 body) ----
    int o = Lb - 1056;                   // 0..511
    int c = o & 7;
    int by = c + 8 * ((o >> 3) & 7);
    int bx = 1 + (o >> 6);               // 1..8
    int wrow = (wave >> 1) * 64;
    int wcol = (wave & 1) * 64;

    const uint16_t* Ab = xb + (size_t)by * 8 * 32 * 512;
    const uint16_t* Bb = wT + (size_t)bx * 8 * 32 * 512;

    const uint16_t* gp = (wave >> 1) ? Bb : Ab;
    uint16_t*       sp = (wave >> 1) ? sB : sA;
    int rb0 = (wave & 1) * 4;

    f32x4 acc[4][4];
    #pragma unroll
    for (int mt = 0; mt < 4; mt++)
      #pragma unroll
      for (int nt = 0; nt < 4; nt++) {
        f32x4 z = {0.0f, 0.0f, 0.0f, 0.0f};
        acc[mt][nt] = z;
      }

    for (int kbi = 0; kbi < 32; kbi += 2) {
      #pragma unroll
      for (int uu = 0; uu < 8; uu++) {
        int rbu = rb0 + (uu >> 1), kk = uu & 1;
        gload16(gp + ((size_t)rbu * 32 + kbi + kk) * 512 + lane * 8,
                sp + (rbu * 2 + kk) * 512);
      }
      __syncthreads();
      #pragma unroll
      for (int kk = 0; kk < 2; kk++) {
        short8 fa[4], fb[4];
        #pragma unroll
        for (int mt = 0; mt < 4; mt++)
          fa[mt] = *(const short8*)(sA + (((wave >> 1) * 4 + mt) * 2 + kk) * 512 + lane * 8);
        #pragma unroll
        for (int nt = 0; nt < 4; nt++)
          fb[nt] = *(const short8*)(sB + (((wave & 1) * 4 + nt) * 2 + kk) * 512 + lane * 8);
        #pragma unroll
        for (int mt = 0; mt < 4; mt++)
          #pragma unroll
          for (int nt = 0; nt < 4; nt++)
            acc[mt][nt] = __builtin_amdgcn_mfma_f32_16x16x32_bf16(
                fa[mt], fb[nt], acc[mt][nt], 0, 0, 0);
      }
      __syncthreads();
    }

    int b = by >> 4;                     // batch
    uint16_t* vt = vT + (size_t)b * DV * S_;
    #pragma unroll
    for (int nt = 0; nt < 4; nt++) {
      int n = (bx - 1) * 128 + wcol + nt * 16 + lane16;   // 0..1023
      float bb = bv[n];
      #pragma unroll
      for (int mt = 0; mt < 4; mt++) {
        int j0l = (by & 15) * 128 + wrow + mt * 16 + quad * 4;
        uint16_t v0 = f32_to_bf16(silu_f(acc[mt][nt][0] + bb));
        uint16_t v1 = f32_to_bf16(silu_f(acc[mt][nt][1] + bb));
        uint16_t v2 = f32_to_bf16(silu_f(acc[mt][nt][2] + bb));
        uint16_t v3 = f32_to_bf16(silu_f(acc[mt][nt][3] + bb));
        size_t off = (size_t)((n >> 4) * 64 + (j0l >> 5)) * 512 +
                     ((j0l >> 3) & 3) * 128 + (n & 15) * 8 + (j0l & 7);
        uint2 pk;
        pk.x = (uint32_t)v0 | ((uint32_t)v1 << 16);
        pk.y = (uint32_t)v2 | ((uint32_t)v3 << 16);
        *(uint2*)(vt + off) = pk;
      }
    }
  }
}

// ---- out = attn @ v, fp32 out (R14, unchanged) ------------------------------
__global__ __launch_bounds__(256, 3) void k_gemm_out(
    const uint16_t* __restrict__ attn, const uint16_t* __restrict__ vT,
    float* __restrict__ out)
{
  int L = blockIdx.x;                    // 0..511
  int c = L & 7, m = L >> 3;             // c: XCD residue, m: 0..63
  int bt = c >> 1;                       // one batch per XCD pair-residue
  int nx = (c & 1) * 4 + (m & 3);        // 0..7
  int it = 15 - (m >> 2);                // descending -> LPT
  int nkb = 4 * it + 4;                  // causal K bound (k-blocks, even)
  int lane = threadIdx.x & 63;
  int wave = threadIdx.x >> 6;
  int lane16 = lane & 15;
  int quad = lane >> 4;
  int wrow = (wave >> 1) * 64;
  int wcol = (wave & 1) * 64;

  __shared__ uint16_t sA[8 * 2 * 512];
  __shared__ uint16_t sB[8 * 2 * 512];

  const uint16_t* Ab = vT + (size_t)bt * DV * S_ + (size_t)nx * 8 * 64 * 512;
  const uint16_t* Bb = attn + (size_t)bt * S_ * S_ + (size_t)it * 8 * 64 * 512;

  const uint16_t* gp = (wave >> 1) ? Bb : Ab;
  uint16_t*       sp = (wave >> 1) ? sB : sA;
  int rb0 = (wave & 1) * 4;

  f32x4 acc[4][4];
  #pragma unroll
  for (int mt = 0; mt < 4; mt++)
    #pragma unroll
    for (int nt = 0; nt < 4; nt++) {
      f32x4 z = {0.0f, 0.0f, 0.0f, 0.0f};
      acc[mt][nt] = z;
    }

  for (int kbi = 0; kbi < nkb; kbi += 2) {
    #pragma unroll
    for (int uu = 0; uu < 8; uu++) {
      int rbu = rb0 + (uu >> 1), kk = uu & 1;
      gload16(gp + ((size_t)rbu * 64 + kbi + kk) * 512 + lane * 8,
              sp + (rbu * 2 + kk) * 512);
    }
    __syncthreads();
    #pragma unroll
    for (int kk = 0; kk < 2; kk++) {
      short8 fa[4], fb[4];
      #pragma unroll
      for (int mt = 0; mt < 4; mt++)
        fa[mt] = *(const short8*)(sA + (((wave & 1) * 4 + mt) * 2 + kk) * 512 + lane * 8);
      #pragma unroll
      for (int nt = 0; nt < 4; nt++)
        fb[nt] = *(const short8*)(sB + (((wave >> 1) * 4 + nt) * 2 + kk) * 512 + lane * 8);
      #pragma unroll
      for (int mt = 0; mt < 4; mt++)
        #pragma unroll
        for (int nt = 0; nt < 4; nt++)
          acc[mt][nt] = __builtin_amdgcn_mfma_f32_16x16x32_bf16(
              fa[mt], fb[nt], acc[mt][nt], 0, 0, 0);
    }
    __syncthreads();
  }

  float* ob = out + ((size_t)bt * S_ + it * 128 + wrow) * DV + nx * 128 + wcol;
  #pragma unroll
  for (int nt = 0; nt < 4; nt++) {
    int i = nt * 16 + lane16;
    #pragma unroll
    for (int mt = 0; mt < 4; mt++) {
      int n = mt * 16 + quad * 4;
      *(float4*)(ob + (size_t)i * DV + n) = *(float4*)&acc[mt][nt];
    }
  }
}

// ---------------------------------------------------------------------------

extern "C" void kernel_launch(void* const* d_in, const int* in_sizes, int n_in,
                              void* d_out, int out_size, void* d_ws, size_t ws_size,
                              hipStream_t stream)
{
  const float* x     = (const float*)d_in[0];
  const float* wqk   = (const float*)d_in[1];
  const float* bqk   = (const float*)d_in[2];
  const float* gamma = (const float*)d_in[3];
  const float* beta  = (const float*)d_in[4];
  const float* wv    = (const float*)d_in[5];
  const float* bv    = (const float*)d_in[6];
  const float* rel   = (const float*)d_in[7];
  float* out = (float*)d_out;

  char* ws = (char*)d_ws;
  size_t off = 0;
  uint16_t* xb     = (uint16_t*)(ws + off); off += (size_t)B_ * S_ * DIM_ * 2;  // 16 MB
  uint16_t* wT     = (uint16_t*)(ws + off); off += (size_t)NQV * DIM_ * 2;      // 2.25 MB
  uint16_t* qb     = (uint16_t*)(ws + off); off += (size_t)B_ * S_ * DQK * 2;   // 2 MB
  uint16_t* kb     = (uint16_t*)(ws + off); off += (size_t)B_ * S_ * DQK * 2;   // 2 MB
  uint16_t* vT     = (uint16_t*)(ws + off); off += (size_t)B_ * DV * S_ * 2;    // 16 MB
  uint16_t* attn   = (uint16_t*)(ws + off); off += (size_t)B_ * S_ * S_ * 2;    // 32 MB
  float*    bias_n = (float*)(ws + off);    off += (size_t)S_ * 4;              // 8 KB

  k_prep<<<dim3(4673), dim3(256), 0, stream>>>(x, wqk, wv, rel, xb, wT, bias_n);
  k_gemm_qk<<<dim3(64), dim3(256), 0, stream>>>(
      xb, wT, bqk, gamma, beta, qb, kb);
  k_simv<<<dim3(1568), dim3(256), 0, stream>>>(
      qb, kb, bias_n, attn, xb, wT, bv, vT);
  k_gemm_out<<<dim3(512), dim3(256), 0, stream>>>(
      attn, vT, out);
}

// Round 9
// 173.033 us; speedup vs baseline: 2.3070x; 1.0606x over previous
//
#include <hip/hip_runtime.h>
#include <stdint.h>

// ---------------------------------------------------------------------------
// SingleHeadedAttention (Mega-style, laplacian attn fn, causal, T5 rel bias)
// B=4, S=2048, DIM=1024, DQK=128, DV=1024.  fp32 in/out, bf16 MFMA internals.
// R17: R16's qk/simv split REVERTED (qk alone = mostly-idle serial launch;
//   regression 171->183.5). Back to R14 structure + occupancy bumps only:
//   - qkv/out launch bounds (256,3) -> (256,4): 4 blocks/CU (LDS allows 5).
//   - sim (128,4) -> (128,6) + DEPTH4 full-unroll (52 VGPR measured in R16,
//     fits the ~80 cap at 6 waves/EU): 16 -> 24 waves/CU.
//   All GEMMs measured latency-bound (MfmaUtil<=17, VALU<=28, HBM<=19%, occ
//   ~22%, 0 bank conflicts) -> TLP is the cheapest remaining lever.
// R15 lesson (kept): NO cross-block data deps in-launch (agent fences+spin
//   serialized to 399us).
// R14: LDS-staged 128x128 GEMM bodies (global_load_lds w=16, BK=64,
//   2-barrier loop). R13: XCD-pinned grids, fused prep. R12: out swapped
//   operands (float4 stores), LPT. R11: sim 32x64 wave tiles, triangle grid.
// R10: branchless erf; swapped QK^T.
//   TILED: element (row,k) of [R][K] at
//     ((row>>4)*(K>>5) + (k>>5))*512 + ((k>>3)&3)*128 + (row&15)*8 + (k&7).
// ---------------------------------------------------------------------------

#define B_   4
#define S_   2048
#define DIM_ 1024
#define DQK  128
#define DV   1024
#define NQV  1152

typedef __attribute__((ext_vector_type(8))) short short8;   // 8 bf16
typedef __attribute__((ext_vector_type(4))) float f32x4;    // MFMA C/D

__device__ __forceinline__ uint16_t f32_to_bf16(float f) {
  uint32_t u = __float_as_uint(f);
  u += 0x7FFFu + ((u >> 16) & 1u);          // round-to-nearest-even
  return (uint16_t)(u >> 16);
}

__device__ __forceinline__ uint32_t pack_bf16(float a, float b) {
  return (uint32_t)f32_to_bf16(a) | ((uint32_t)f32_to_bf16(b) << 16);
}

__device__ __forceinline__ float silu_f(float x) {
  return x * __builtin_amdgcn_rcpf(1.0f + __expf(-x));
}

// 0.5*(1+erf((x-mu)/(std*sqrt2))), mu=sqrt(0.5), std=sqrt(pi/4).
// Branchless Abramowitz-Stegun 7.1.26 erf approx, |eps| <= 1.5e-7.
__device__ __forceinline__ float laplacian_attn(float x) {
  float z  = (x - 0.70710678118654752f) * 0.79788456080286536f;
  float az = fabsf(z);
  float t  = __builtin_amdgcn_rcpf(fmaf(0.3275911f, az, 1.0f));
  float w  = fmaf(1.061405429f, t, -1.453152027f);
  w = fmaf(w, t, 1.421413741f);
  w = fmaf(w, t, -0.284496736f);
  w = fmaf(w, t, 0.254829592f);
  float P  = w * t;
  float E  = __expf(-z * z);
  float ea = fmaf(-P, E, 1.0f);            // erf(|z|)
  float er = copysignf(ea, z);
  return fmaf(0.5f, er, 0.5f);
}

// global->LDS DMA, 16B per lane.
__device__ __forceinline__ void gload16(const uint16_t* g, uint16_t* l) {
  __builtin_amdgcn_global_load_lds(
      (const __attribute__((address_space(1))) void*)g,
      (__attribute__((address_space(3))) void*)l, 16, 0, 0);
}

// ---- wave-private MTxNT (16-row units) GEMM on TILED operands -------------
template <int MT, int NT, int DEPTH>
__device__ __forceinline__ void wave_gemm_t(
    const uint16_t* __restrict__ A, int KBa, int rbA,
    const uint16_t* __restrict__ Bt, int KBb, int rbB,
    int nkb, f32x4 acc[MT][NT])
{
  const int lane = threadIdx.x & 63;

  const uint16_t* pa[MT];
  const uint16_t* pb[NT];
  #pragma unroll
  for (int mt = 0; mt < MT; mt++)
    pa[mt] = A + (size_t)(rbA + mt) * KBa * 512 + lane * 8;
  #pragma unroll
  for (int nt = 0; nt < NT; nt++)
    pb[nt] = Bt + (size_t)(rbB + nt) * KBb * 512 + lane * 8;

  #pragma unroll
  for (int mt = 0; mt < MT; mt++)
    #pragma unroll
    for (int nt = 0; nt < NT; nt++) {
      f32x4 z = {0.0f, 0.0f, 0.0f, 0.0f};
      acc[mt][nt] = z;
    }

  short8 fa0[MT], fb0[NT], fa1[MT], fb1[NT];

  auto loads = [&](short8 fa[MT], short8 fb[NT], int kb) {
    #pragma unroll
    for (int mt = 0; mt < MT; mt++)
      fa[mt] = *(const short8*)(pa[mt] + (size_t)kb * 512);
    #pragma unroll
    for (int nt = 0; nt < NT; nt++)
      fb[nt] = *(const short8*)(pb[nt] + (size_t)kb * 512);
  };
  auto mfmas = [&](short8 fa[MT], short8 fb[NT]) {
    #pragma unroll
    for (int mt = 0; mt < MT; mt++)
      #pragma unroll
      for (int nt = 0; nt < NT; nt++)
        acc[mt][nt] = __builtin_amdgcn_mfma_f32_16x16x32_bf16(
            fa[mt], fb[nt], acc[mt][nt], 0, 0, 0);
  };

  if constexpr (DEPTH == 2) {
    loads(fa0, fb0, 0);
    loads(fa1, fb1, 1);
    for (int kb = 2; kb < nkb; kb += 2) {
      mfmas(fa0, fb0);
      loads(fa0, fb0, kb);
      mfmas(fa1, fb1);
      loads(fa1, fb1, kb + 1);
    }
    mfmas(fa0, fb0);
    mfmas(fa1, fb1);
  } else {
    short8 fa2[MT], fb2[NT], fa3[MT], fb3[NT];
    loads(fa0, fb0, 0);
    loads(fa1, fb1, 1);
    loads(fa2, fb2, 2);
    loads(fa3, fb3, 3);
    for (int kb = 4; kb < nkb; kb += 4) {
      mfmas(fa0, fb0);
      loads(fa0, fb0, kb);
      mfmas(fa1, fb1);
      loads(fa1, fb1, kb + 1);
      mfmas(fa2, fb2);
      loads(fa2, fb2, kb + 2);
      mfmas(fa3, fb3);
      loads(fa3, fb3, kb + 3);
    }
    mfmas(fa0, fb0);
    mfmas(fa1, fb1);
    mfmas(fa2, fb2);
    mfmas(fa3, fb3);
  }
}

// ---- fused prep kernel -----------------------------------------------------
__global__ __launch_bounds__(256) void k_prep(
    const float* __restrict__ x, const float* __restrict__ wqk,
    const float* __restrict__ wv, const float* __restrict__ rel,
    uint16_t* __restrict__ xb, uint16_t* __restrict__ wT,
    float* __restrict__ bias_n)
{
  int blk = blockIdx.x;
  if (blk < 4096) {
    int t = blk * 256 + threadIdx.x;           // 0 .. 8192*128-1
    int i16 = t & 15, oct = (t >> 4) & 3, kb = (t >> 6) & 31, ib = t >> 11;
    const float* src = x + (size_t)(ib * 16 + i16) * DIM_ + kb * 32 + oct * 8;
    float4 a = *(const float4*)src;
    float4 b = *(const float4*)(src + 4);
    short8 o;
    o[0] = f32_to_bf16(a.x); o[1] = f32_to_bf16(a.y);
    o[2] = f32_to_bf16(a.z); o[3] = f32_to_bf16(a.w);
    o[4] = f32_to_bf16(b.x); o[5] = f32_to_bf16(b.y);
    o[6] = f32_to_bf16(b.z); o[7] = f32_to_bf16(b.w);
    *(short8*)(xb + (size_t)t * 8) = o;
  } else if (blk < 4672) {
    int t = (blk - 4096) * 256 + threadIdx.x;  // 0 .. 1152*128-1
    int n16 = t & 15, oct = (t >> 4) & 3, kb = (t >> 6) & 31, nb = t >> 11;
    int n = nb * 16 + n16;
    int k0 = kb * 32 + oct * 8;
    short8 o;
    if (n < DQK) {
      #pragma unroll
      for (int j = 0; j < 8; j++)
        o[j] = f32_to_bf16(wqk[(size_t)(k0 + j) * DQK + n]);
    } else {
      int nn = n - DQK;
      #pragma unroll
      for (int j = 0; j < 8; j++)
        o[j] = f32_to_bf16(wv[(size_t)(k0 + j) * DV + nn]);
    }
    *(short8*)(wT + (size_t)t * 8) = o;
  } else {
    for (int n = threadIdx.x; n < S_; n += 256) {
      int bucket;
      if (n < 16) {
        bucket = n;
      } else {
        float tt = logf((float)n * 0.0625f) / 2.0794415416798357f * 16.0f;
        int vl = 16 + (int)tt;
        bucket = vl < 31 ? vl : 31;
      }
      bias_n[n] = rel[bucket] * 11.313708498984761f;
    }
  }
}

// ---- GEMM kernels ----------------------------------------------------------

// fused projections, LDS-staged. 1-D grid 576, XCD-pinned (9 bx of a by per
// XCD). bx==0: q/k epilogue (SWAPPED operands -> packed 8B stores);
// bx>=1: v -> vT TILED.
__global__ __launch_bounds__(256, 4) void k_gemm_qkv(
    const uint16_t* __restrict__ xb, const uint16_t* __restrict__ wT,
    const float* __restrict__ bqk, const float* __restrict__ gamma,
    const float* __restrict__ beta, const float* __restrict__ bv,
    uint16_t* __restrict__ qb, uint16_t* __restrict__ kb,
    uint16_t* __restrict__ vT)
{
  int L = blockIdx.x;                    // 0..575
  int c = L & 7;
  int idx = L >> 3;                      // 0..71
  int by = c + 8 * (idx / 9);
  int bx = idx % 9;
  int lane = threadIdx.x & 63;
  int wave = threadIdx.x >> 6;
  int lane16 = lane & 15;
  int quad = lane >> 4;
  int wrow = (wave >> 1) * 64;
  int wcol = (wave & 1) * 64;

  __shared__ uint16_t sA[8 * 2 * 512];   // [rbu][kk][512]
  __shared__ uint16_t sB[8 * 2 * 512];

  const uint16_t *Ab, *Bb;
  if (bx == 0) { Ab = wT;                              Bb = xb + (size_t)by * 8 * 32 * 512; }
  else         { Ab = xb + (size_t)by * 8 * 32 * 512;  Bb = wT + (size_t)bx * 8 * 32 * 512; }

  const uint16_t* gp = (wave >> 1) ? Bb : Ab;
  uint16_t*       sp = (wave >> 1) ? sB : sA;
  int rb0 = (wave & 1) * 4;

  f32x4 acc[4][4];
  #pragma unroll
  for (int mt = 0; mt < 4; mt++)
    #pragma unroll
    for (int nt = 0; nt < 4; nt++) {
      f32x4 z = {0.0f, 0.0f, 0.0f, 0.0f};
      acc[mt][nt] = z;
    }

  for (int kbi = 0; kbi < 32; kbi += 2) {
    #pragma unroll
    for (int uu = 0; uu < 8; uu++) {
      int rbu = rb0 + (uu >> 1), kk = uu & 1;
      gload16(gp + ((size_t)rbu * 32 + kbi + kk) * 512 + lane * 8,
              sp + (rbu * 2 + kk) * 512);
    }
    __syncthreads();
    #pragma unroll
    for (int kk = 0; kk < 2; kk++) {
      short8 fa[4], fb[4];
      #pragma unroll
      for (int mt = 0; mt < 4; mt++)
        fa[mt] = *(const short8*)(sA + (((wave >> 1) * 4 + mt) * 2 + kk) * 512 + lane * 8);
      #pragma unroll
      for (int nt = 0; nt < 4; nt++)
        fb[nt] = *(const short8*)(sB + (((wave & 1) * 4 + nt) * 2 + kk) * 512 + lane * 8);
      #pragma unroll
      for (int mt = 0; mt < 4; mt++)
        #pragma unroll
        for (int nt = 0; nt < 4; nt++)
          acc[mt][nt] = __builtin_amdgcn_mfma_f32_16x16x32_bf16(
              fa[mt], fb[nt], acc[mt][nt], 0, 0, 0);
    }
    __syncthreads();
  }

  if (bx == 0) {
    int ibase = by * 128 + (wave & 1) * 64;
    int cbase = (wave >> 1) * 64;
    #pragma unroll
    for (int mt = 0; mt < 4; mt++) {
      int c0 = cbase + mt * 16 + quad * 4;
      float4 bb = *(const float4*)(bqk + c0);
      float4 g0 = *(const float4*)(gamma + c0);
      float4 g1 = *(const float4*)(gamma + DQK + c0);
      float4 e0 = *(const float4*)(beta + c0);
      float4 e1 = *(const float4*)(beta + DQK + c0);
      size_t coff = (size_t)(c0 >> 5) * 512 + ((c0 >> 3) & 3) * 128 + (c0 & 7);
      #pragma unroll
      for (int nt = 0; nt < 4; nt++) {
        int i = ibase + nt * 16 + lane16;
        float s0 = silu_f(acc[mt][nt][0] + bb.x);
        float s1 = silu_f(acc[mt][nt][1] + bb.y);
        float s2 = silu_f(acc[mt][nt][2] + bb.z);
        float s3 = silu_f(acc[mt][nt][3] + bb.w);
        uint2 pq, pk;
        pq.x = pack_bf16(fmaf(s0, g0.x, e0.x), fmaf(s1, g0.y, e0.y));
        pq.y = pack_bf16(fmaf(s2, g0.z, e0.z), fmaf(s3, g0.w, e0.w));
        pk.x = pack_bf16(fmaf(s0, g1.x, e1.x), fmaf(s1, g1.y, e1.y));
        pk.y = pack_bf16(fmaf(s2, g1.z, e1.z), fmaf(s3, g1.w, e1.w));
        size_t off = (size_t)(i >> 4) * 4 * 512 + (size_t)(i & 15) * 8 + coff;
        *(uint2*)(qb + off) = pq;
        *(uint2*)(kb + off) = pk;
      }
    }
  } else {
    int b = by >> 4;                               // batch (by*128 / 2048)
    uint16_t* vt = vT + (size_t)b * DV * S_;
    #pragma unroll
    for (int nt = 0; nt < 4; nt++) {
      int n = (bx - 1) * 128 + wcol + nt * 16 + lane16;   // 0..1023
      float bb = bv[n];
      #pragma unroll
      for (int mt = 0; mt < 4; mt++) {
        int j0l = (by & 15) * 128 + wrow + mt * 16 + quad * 4; // local seq
        uint16_t v0 = f32_to_bf16(silu_f(acc[mt][nt][0] + bb));
        uint16_t v1 = f32_to_bf16(silu_f(acc[mt][nt][1] + bb));
        uint16_t v2 = f32_to_bf16(silu_f(acc[mt][nt][2] + bb));
        uint16_t v3 = f32_to_bf16(silu_f(acc[mt][nt][3] + bb));
        size_t off = (size_t)((n >> 4) * 64 + (j0l >> 5)) * 512 +
                     ((j0l >> 3) & 3) * 128 + (n & 15) * 8 + (j0l & 7);
        uint2 pk;
        pk.x = (uint32_t)v0 | ((uint32_t)v1 << 16);
        pk.y = (uint32_t)v2 | ((uint32_t)v3 << 16);
        *(uint2*)(vt + off) = pk;
      }
    }
  }
}

// attn = laplacian(q@k^T/S + bias[i-j]) causal, TILED bf16 per batch.
// 64x64 tile per 128-thread block (2 waves); exact causal triangle grid.
// SWAPPED: A = kb rows (j), B = qb rows (i). DEPTH4: single latency exposure.
// (128,6): 24 waves/CU (52 VGPR measured in R16 -> fits ~80 cap).
__global__ __launch_bounds__(128, 6) void k_gemm_sim(
    const uint16_t* __restrict__ qb, const uint16_t* __restrict__ kb,
    const float* __restrict__ bias_n, uint16_t* __restrict__ attn)
{
  int b = blockIdx.x;                    // 0..527 triangular tile index
  int bt = blockIdx.y;                   // batch
  int it = (int)((sqrtf(8.0f * (float)b + 1.0f) - 1.0f) * 0.5f);
  while ((it + 1) * (it + 2) / 2 <= b) ++it;
  while (it * (it + 1) / 2 > b) --it;
  int jt = b - it * (it + 1) / 2;        // 0..it

  int lane = threadIdx.x & 63;
  int wave = threadIdx.x >> 6;           // 0..1 (i-halves of the 64-row tile)
  int lane16 = lane & 15;
  int quad = lane >> 4;

  f32x4 acc[4][2];
  wave_gemm_t<4,2,4>(kb, 4, bt * 128 + jt * 4,
                     qb, 4, bt * 128 + it * 4 + wave * 2,
                     4, acc);

  uint16_t* ab = attn + (size_t)bt * S_ * S_;
  int ibase = it * 64 + wave * 32;
  int jbase = jt * 64;
  #pragma unroll
  for (int nt = 0; nt < 2; nt++) {
    int i = ibase + nt * 16 + lane16;
    size_t irow = (size_t)(i >> 4) * 64 * 512 + (size_t)(i & 15) * 8;
    #pragma unroll
    for (int mt = 0; mt < 4; mt++) {
      int j0 = jbase + mt * 16 + quad * 4;
      float v[4];
      #pragma unroll
      for (int r = 0; r < 4; r++) {
        int j = j0 + r;
        float aval = 0.0f;
        if (j <= i) {
          float sim = acc[mt][nt][r] * (1.0f / 2048.0f) + bias_n[i - j];
          aval = laplacian_attn(sim);
        }
        v[r] = aval;
      }
      uint2 pk;
      pk.x = pack_bf16(v[0], v[1]);
      pk.y = pack_bf16(v[2], v[3]);
      size_t off = irow + (size_t)(j0 >> 5) * 512 + ((j0 >> 3) & 3) * 128 +
                   (j0 & 7);
      *(uint2*)(ab + off) = pk;
    }
  }
}

// out = attn @ v, fp32 out, LDS-staged.  1-D grid 512: XCD c serves ONE bt
// (c>>1); nx=(c&1)*4+(m&3); it=15-(m>>2) (LPT desc). SWAPPED operands:
// A=vT (n rows, staged sA), B=attn (i rows, staged sB) -> float4 stores.
__global__ __launch_bounds__(256, 4) void k_gemm_out(
    const uint16_t* __restrict__ attn, const uint16_t* __restrict__ vT,
    float* __restrict__ out)
{
  int L = blockIdx.x;                    // 0..511
  int c = L & 7, m = L >> 3;             // c: XCD residue, m: 0..63
  int bt = c >> 1;                       // one batch per XCD pair-residue
  int nx = (c & 1) * 4 + (m & 3);        // 0..7
  int it = 15 - (m >> 2);                // descending -> LPT
  int nkb = 4 * it + 4;                  // causal K bound (k-blocks, even)
  int lane = threadIdx.x & 63;
  int wave = threadIdx.x >> 6;
  int lane16 = lane & 15;
  int quad = lane >> 4;
  int wrow = (wave >> 1) * 64;
  int wcol = (wave & 1) * 64;

  __shared__ uint16_t sA[8 * 2 * 512];
  __shared__ uint16_t sB[8 * 2 * 512];

  const uint16_t* Ab = vT + (size_t)bt * DV * S_ + (size_t)nx * 8 * 64 * 512;
  const uint16_t* Bb = attn + (size_t)bt * S_ * S_ + (size_t)it * 8 * 64 * 512;

  const uint16_t* gp = (wave >> 1) ? Bb : Ab;
  uint16_t*       sp = (wave >> 1) ? sB : sA;
  int rb0 = (wave & 1) * 4;

  f32x4 acc[4][4];
  #pragma unroll
  for (int mt = 0; mt < 4; mt++)
    #pragma unroll
    for (int nt = 0; nt < 4; nt++) {
      f32x4 z = {0.0f, 0.0f, 0.0f, 0.0f};
      acc[mt][nt] = z;
    }

  for (int kbi = 0; kbi < nkb; kbi += 2) {
    #pragma unroll
    for (int uu = 0; uu < 8; uu++) {
      int rbu = rb0 + (uu >> 1), kk = uu & 1;
      gload16(gp + ((size_t)rbu * 64 + kbi + kk) * 512 + lane * 8,
              sp + (rbu * 2 + kk) * 512);
    }
    __syncthreads();
    #pragma unroll
    for (int kk = 0; kk < 2; kk++) {
      short8 fa[4], fb[4];
      #pragma unroll
      for (int mt = 0; mt < 4; mt++)
        fa[mt] = *(const short8*)(sA + (((wave & 1) * 4 + mt) * 2 + kk) * 512 + lane * 8);
      #pragma unroll
      for (int nt = 0; nt < 4; nt++)
        fb[nt] = *(const short8*)(sB + (((wave >> 1) * 4 + nt) * 2 + kk) * 512 + lane * 8);
      #pragma unroll
      for (int mt = 0; mt < 4; mt++)
        #pragma unroll
        for (int nt = 0; nt < 4; nt++)
          acc[mt][nt] = __builtin_amdgcn_mfma_f32_16x16x32_bf16(
              fa[mt], fb[nt], acc[mt][nt], 0, 0, 0);
    }
    __syncthreads();
  }

  float* ob = out + ((size_t)bt * S_ + it * 128 + wrow) * DV + nx * 128 + wcol;
  #pragma unroll
  for (int nt = 0; nt < 4; nt++) {
    int i = nt * 16 + lane16;
    #pragma unroll
    for (int mt = 0; mt < 4; mt++) {
      int n = mt * 16 + quad * 4;
      *(float4*)(ob + (size_t)i * DV + n) = *(float4*)&acc[mt][nt];
    }
  }
}

// ---------------------------------------------------------------------------

extern "C" void kernel_launch(void* const* d_in, const int* in_sizes, int n_in,
                              void* d_out, int out_size, void* d_ws, size_t ws_size,
                              hipStream_t stream)
{
  const float* x     = (const float*)d_in[0];
  const float* wqk   = (const float*)d_in[1];
  const float* bqk   = (const float*)d_in[2];
  const float* gamma = (const float*)d_in[3];
  const float* beta  = (const float*)d_in[4];
  const float* wv    = (const float*)d_in[5];
  const float* bv    = (const float*)d_in[6];
  const float* rel   = (const float*)d_in[7];
  float* out = (float*)d_out;

  char* ws = (char*)d_ws;
  size_t off = 0;
  uint16_t* xb     = (uint16_t*)(ws + off); off += (size_t)B_ * S_ * DIM_ * 2;  // 16 MB
  uint16_t* wT     = (uint16_t*)(ws + off); off += (size_t)NQV * DIM_ * 2;      // 2.25 MB
  uint16_t* qb     = (uint16_t*)(ws + off); off += (size_t)B_ * S_ * DQK * 2;   // 2 MB
  uint16_t* kb     = (uint16_t*)(ws + off); off += (size_t)B_ * S_ * DQK * 2;   // 2 MB
  uint16_t* vT     = (uint16_t*)(ws + off); off += (size_t)B_ * DV * S_ * 2;    // 16 MB
  uint16_t* attn   = (uint16_t*)(ws + off); off += (size_t)B_ * S_ * S_ * 2;    // 32 MB
  float*    bias_n = (float*)(ws + off);    off += (size_t)S_ * 4;              // 8 KB

  k_prep<<<dim3(4673), dim3(256), 0, stream>>>(x, wqk, wv, rel, xb, wT, bias_n);

  k_gemm_qkv<<<dim3(576), dim3(256), 0, stream>>>(
      xb, wT, bqk, gamma, beta, bv, qb, kb, vT);
  k_gemm_sim<<<dim3(528, B_), dim3(128), 0, stream>>>(
      qb, kb, bias_n, attn);
  k_gemm_out<<<dim3(512), dim3(256), 0, stream>>>(
      attn, vT, out);
}